// Round 1
// baseline (246.413 us; speedup 1.0000x reference)
//
#include <hip/hip_runtime.h>

typedef __attribute__((ext_vector_type(4))) float f32x4;
typedef __attribute__((ext_vector_type(8))) short bf16x8;

#define NN 32
#define FV 256

__device__ __forceinline__ unsigned short bf16_rne(float x) {
    unsigned int u = __float_as_uint(x);
    u += 0x7FFFu + ((u >> 16) & 1u);
    return (unsigned short)(u >> 16);
}
__device__ __forceinline__ float bf16_f(unsigned short h) {
    return __uint_as_float(((unsigned int)h) << 16);
}

// K0: split W into hi/lo bf16 and pack in MFMA B-fragment lane order.
// Layout: wpack[half*131072], hi then lo (65536 shorts each).
// frag id t = (ct*8 + ks)*64 + l ; element e: h = ct*16+(l&15), f = ks*32+(l>>4)*8+e
__global__ __launch_bounds__(256) void pack_weights(
    const float* __restrict__ Wself, const float* __restrict__ Wneigh,
    unsigned short* __restrict__ wpack)
{
    const float* W = blockIdx.y ? Wneigh : Wself;
    unsigned short* hi = wpack + (size_t)blockIdx.y * 131072;
    unsigned short* lo = hi + 65536;
    int t = blockIdx.x * 256 + threadIdx.x;   // 0..8191
    int l = t & 63;
    int ks = (t >> 6) & 7;
    int ct = t >> 9;
    int h = ct * 16 + (l & 15);
    int f0 = ks * 32 + ((l >> 4) << 3);
    const float* src = W + h * 256 + f0;
    f32x4 a = *(const f32x4*)src;
    f32x4 b = *(const f32x4*)(src + 4);
    bf16x8 hv, lv;
#pragma unroll
    for (int e = 0; e < 8; ++e) {
        float x = (e < 4) ? a[e] : b[e - 4];
        unsigned short h16 = bf16_rne(x);
        hv[e] = (short)h16;
        lv[e] = (short)bf16_rne(x - bf16_f(h16));
    }
    *(bf16x8*)(hi + (size_t)t * 8) = hv;
    *(bf16x8*)(lo + (size_t)t * 8) = lv;
}

// K1: gather self row + mean-pool 32 neighbor rows, write f32 to out in place:
// out[b, 0:256] = emb[x0[b]], out[b, 256:512] = mean_j emb[x1[b,j]]
__global__ __launch_bounds__(256) void gather_pool(
    const int* __restrict__ x0, const int* __restrict__ x1,
    const float* __restrict__ emb, float* __restrict__ out)
{
    int b = blockIdx.x;
    int tid = threadIdx.x;
    int g = tid >> 6, l = tid & 63;
    __shared__ f32x4 red[3][64];

    const int* xr = x1 + b * NN;
    int idx[8];
#pragma unroll
    for (int jj = 0; jj < 8; ++jj) idx[jj] = xr[g + jj * 4];

    int sidx = 0;
    if (g == 0) sidx = x0[b];

    f32x4 acc = {0.f, 0.f, 0.f, 0.f};
#pragma unroll
    for (int jj = 0; jj < 8; ++jj) {
        const f32x4* row = (const f32x4*)(emb + (size_t)idx[jj] * FV);
        acc += row[l];
    }
    f32x4 s = {0.f, 0.f, 0.f, 0.f};
    if (g == 0) s = ((const f32x4*)(emb + (size_t)sidx * FV))[l];

    if (g > 0) red[g - 1][l] = acc;
    __syncthreads();
    if (g == 0) {
        f32x4 p = acc + red[0][l] + red[1][l] + red[2][l];
        p *= (1.0f / 32.0f);
        f32x4* o = (f32x4*)(out + (size_t)b * 512);
        o[l] = s;
        o[64 + l] = p;
    }
}

// K2: in-place dual GEMM + bias + relu.
// block (bx, half): rows b0..b0+64, reads out[rows, half*256 : +256] (f32),
// splits into bf16 hi/lo in swizzled LDS, 3-pass MFMA vs packed W, writes back same region.
__global__ __launch_bounds__(256) void dual_gemm(
    const float* X, const unsigned short* __restrict__ wpack,
    const float* __restrict__ bias_self, const float* __restrict__ bias_neigh,
    float* out)
{
    __shared__ short Xh[64 * 256];
    __shared__ short Xl[64 * 256];
    int half = blockIdx.y;
    int b0 = blockIdx.x * 64;
    int tid = threadIdx.x;

    const unsigned short* Whi = wpack + (size_t)half * 131072;
    const unsigned short* Wlo = Whi + 65536;
    const float* bias = half ? bias_neigh : bias_self;

    // Phase A: load 64x256 f32, split, swizzled LDS store (16B chunks)
#pragma unroll
    for (int it = 0; it < 8; ++it) {
        int c = it * 256 + tid;       // chunk id: 2048 chunks of 8 floats
        int row = c >> 5;             // 0..63
        int k8 = c & 31;              // which 8-float chunk in the row
        const float* src = X + (size_t)(b0 + row) * 512 + half * 256 + k8 * 8;
        f32x4 v0 = *(const f32x4*)src;
        f32x4 v1 = *(const f32x4*)(src + 4);
        bf16x8 hv, lv;
#pragma unroll
        for (int e = 0; e < 8; ++e) {
            float x = (e < 4) ? v0[e] : v1[e - 4];
            unsigned short h16 = bf16_rne(x);
            hv[e] = (short)h16;
            lv[e] = (short)bf16_rne(x - bf16_f(h16));
        }
        int boff = (row * 512 + k8 * 16) ^ ((row & 7) << 4);
        *(bf16x8*)((char*)Xh + boff) = hv;
        *(bf16x8*)((char*)Xl + boff) = lv;
    }
    __syncthreads();

    int w = tid >> 6, l = tid & 63;
    int mh = w & 1;        // M half: rows mh*32..+32
    int nh = w >> 1;       // N half: col tiles nh*8..+8
    int colq = l & 15;     // col within 16x16 tile; also A-row within tile
    int kq = l >> 4;       // k quadrant (8 elems each)

    f32x4 acc[2][8];
#pragma unroll
    for (int c = 0; c < 8; ++c) {
        int ct = nh * 8 + c;
        float bv = bias[ct * 16 + colq];
#pragma unroll
        for (int m = 0; m < 2; ++m) acc[m][c] = {bv, bv, bv, bv};
    }

#pragma unroll
    for (int ks = 0; ks < 8; ++ks) {
        bf16x8 Ah[2], Al[2];
#pragma unroll
        for (int m = 0; m < 2; ++m) {
            int row = mh * 32 + m * 16 + colq;
            int boff = (row * 512 + ks * 64 + (kq << 4)) ^ ((row & 7) << 4);
            Ah[m] = *(const bf16x8*)((const char*)Xh + boff);
            Al[m] = *(const bf16x8*)((const char*)Xl + boff);
        }
#pragma unroll
        for (int c = 0; c < 8; ++c) {
            int ct = nh * 8 + c;
            size_t fo = ((size_t)(ct * 8 + ks) * 64 + l) * 8;
            bf16x8 Bh = *(const bf16x8*)(Whi + fo);
            bf16x8 Bl = *(const bf16x8*)(Wlo + fo);
#pragma unroll
            for (int m = 0; m < 2; ++m) {
                acc[m][c] = __builtin_amdgcn_mfma_f32_16x16x32_bf16(Ah[m], Bh, acc[m][c], 0, 0, 0);
                acc[m][c] = __builtin_amdgcn_mfma_f32_16x16x32_bf16(Al[m], Bh, acc[m][c], 0, 0, 0);
                acc[m][c] = __builtin_amdgcn_mfma_f32_16x16x32_bf16(Ah[m], Bl, acc[m][c], 0, 0, 0);
            }
        }
    }

    // Epilogue: relu + store (bias already in acc init)
#pragma unroll
    for (int m = 0; m < 2; ++m) {
        int rb = mh * 32 + m * 16 + (kq << 2);
#pragma unroll
        for (int c = 0; c < 8; ++c) {
            int col = (nh * 8 + c) * 16 + colq;
            float* o = out + (size_t)(b0 + rb) * 512 + half * 256 + col;
#pragma unroll
            for (int j = 0; j < 4; ++j) {
                o[(size_t)j * 512] = fmaxf(acc[m][c][j], 0.0f);
            }
        }
    }
}

extern "C" void kernel_launch(void* const* d_in, const int* in_sizes, int n_in,
                              void* d_out, int out_size, void* d_ws, size_t ws_size,
                              hipStream_t stream) {
    const int* x0 = (const int*)d_in[0];
    const int* x1 = (const int*)d_in[1];
    const float* emb = (const float*)d_in[2];
    const float* Wself = (const float*)d_in[3];
    const float* bself = (const float*)d_in[4];
    const float* Wneigh = (const float*)d_in[5];
    const float* bneigh = (const float*)d_in[6];
    float* out = (float*)d_out;
    unsigned short* wpack = (unsigned short*)d_ws;  // needs 512 KB

    pack_weights<<<dim3(32, 2), 256, 0, stream>>>(Wself, Wneigh, wpack);
    gather_pool<<<16384, 256, 0, stream>>>(x0, x1, emb, out);
    dual_gemm<<<dim3(256, 2), 256, 0, stream>>>(out, wpack, bself, bneigh, out);
}

// Round 9
// 244.874 us; speedup vs baseline: 1.0063x; 1.0063x over previous
//
#include <hip/hip_runtime.h>

typedef __attribute__((ext_vector_type(4))) float f32x4;
typedef __attribute__((ext_vector_type(8))) short bf16x8;
typedef __attribute__((ext_vector_type(4))) short bf16x4;

#define NN 32
#define FV 256

__device__ __forceinline__ unsigned short bf16_rne(float x) {
    unsigned int u = __float_as_uint(x);
    u += 0x7FFFu + ((u >> 16) & 1u);
    return (unsigned short)(u >> 16);
}
__device__ __forceinline__ float bf16_f(unsigned short h) {
    return __uint_as_float(((unsigned int)h) << 16);
}

// K0: split W into hi/lo bf16 and pack in MFMA B-fragment lane order.
// Layout per half: hi[65536] shorts then lo[65536] shorts.
// frag id t = (ct*8 + ks)*64 + l ; element e: h = ct*16+(l&15), f = ks*32+(l>>4)*8+e
__global__ __launch_bounds__(256) void pack_weights(
    const float* __restrict__ Wself, const float* __restrict__ Wneigh,
    unsigned short* __restrict__ wpack)
{
    const float* W = blockIdx.y ? Wneigh : Wself;
    unsigned short* hi = wpack + (size_t)blockIdx.y * 131072;
    unsigned short* lo = hi + 65536;
    int t = blockIdx.x * 256 + threadIdx.x;   // 0..8191
    int l = t & 63;
    int ks = (t >> 6) & 7;
    int ct = t >> 9;
    int h = ct * 16 + (l & 15);
    int f0 = ks * 32 + ((l >> 4) << 3);
    const float* src = W + h * 256 + f0;
    f32x4 a = *(const f32x4*)src;
    f32x4 b = *(const f32x4*)(src + 4);
    bf16x8 hv, lv;
#pragma unroll
    for (int e = 0; e < 8; ++e) {
        float x = (e < 4) ? a[e] : b[e - 4];
        unsigned short h16 = bf16_rne(x);
        hv[e] = (short)h16;
        lv[e] = (short)bf16_rne(x - bf16_f(h16));
    }
    *(bf16x8*)(hi + (size_t)t * 8) = hv;
    *(bf16x8*)(lo + (size_t)t * 8) = lv;
}

// K1 (main path): gather + pool, emit split-bf16 planes.
// Xhi/Xlo are [16384][512] shorts: cols 0:256 = self, 256:512 = pooled mean.
__global__ __launch_bounds__(256) void gather_pool_split(
    const int* __restrict__ x0, const int* __restrict__ x1,
    const float* __restrict__ emb,
    unsigned short* __restrict__ Xhi, unsigned short* __restrict__ Xlo)
{
    int b = blockIdx.x;
    int tid = threadIdx.x;
    int g = tid >> 6, l = tid & 63;
    __shared__ f32x4 red[3][64];

    const int* xr = x1 + b * NN;
    int idx[8];
#pragma unroll
    for (int jj = 0; jj < 8; ++jj) idx[jj] = xr[g + jj * 4];

    int sidx = 0;
    if (g == 0) sidx = x0[b];

    f32x4 acc = {0.f, 0.f, 0.f, 0.f};
#pragma unroll
    for (int jj = 0; jj < 8; ++jj) {
        const f32x4* row = (const f32x4*)(emb + (size_t)idx[jj] * FV);
        acc += row[l];
    }
    f32x4 s = {0.f, 0.f, 0.f, 0.f};
    if (g == 0) s = ((const f32x4*)(emb + (size_t)sidx * FV))[l];

    if (g > 0) red[g - 1][l] = acc;
    __syncthreads();
    if (g == 0) {
        f32x4 p = acc + red[0][l] + red[1][l] + red[2][l];
        p *= (1.0f / 32.0f);
        bf16x4 sh, sl, ph, pl;
#pragma unroll
        for (int e = 0; e < 4; ++e) {
            unsigned short h16 = bf16_rne(s[e]);
            sh[e] = (short)h16;
            sl[e] = (short)bf16_rne(s[e] - bf16_f(h16));
            unsigned short h2 = bf16_rne(p[e]);
            ph[e] = (short)h2;
            pl[e] = (short)bf16_rne(p[e] - bf16_f(h2));
        }
        size_t base = (size_t)b * 512 + l * 4;
        *(bf16x4*)(Xhi + base)       = sh;
        *(bf16x4*)(Xlo + base)       = sl;
        *(bf16x4*)(Xhi + base + 256) = ph;
        *(bf16x4*)(Xlo + base + 256) = pl;
    }
}

// K1 (fallback path): f32 gather into out[b,0:512]
__global__ __launch_bounds__(256) void gather_pool(
    const int* __restrict__ x0, const int* __restrict__ x1,
    const float* __restrict__ emb, float* __restrict__ xout)
{
    int b = blockIdx.x;
    int tid = threadIdx.x;
    int g = tid >> 6, l = tid & 63;
    __shared__ f32x4 red[3][64];

    const int* xr = x1 + b * NN;
    int idx[8];
#pragma unroll
    for (int jj = 0; jj < 8; ++jj) idx[jj] = xr[g + jj * 4];

    int sidx = 0;
    if (g == 0) sidx = x0[b];

    f32x4 acc = {0.f, 0.f, 0.f, 0.f};
#pragma unroll
    for (int jj = 0; jj < 8; ++jj) {
        const f32x4* row = (const f32x4*)(emb + (size_t)idx[jj] * FV);
        acc += row[l];
    }
    f32x4 s = {0.f, 0.f, 0.f, 0.f};
    if (g == 0) s = ((const f32x4*)(emb + (size_t)sidx * FV))[l];

    if (g > 0) red[g - 1][l] = acc;
    __syncthreads();
    if (g == 0) {
        f32x4 p = acc + red[0][l] + red[1][l] + red[2][l];
        p *= (1.0f / 32.0f);
        f32x4* o = (f32x4*)(xout + (size_t)b * 512);
        o[l] = s;
        o[64 + l] = p;
    }
}

// K2 v3: W-slice in LDS (pre-packed fragment order), A = pre-split bf16 planes
// streamed global->reg. Pure load+MFMA inner loop (no VALU split).
// block (mt, ns, half): rows mt*256..+256, cols half*256 + ns*128..+128.
// 512 threads = 8 waves: wave w -> mg=w>>1 (64 rows), ng=w&1 (4 col-tiles of 16).
__global__ __launch_bounds__(512, 2) void dual_gemm_v3(
    const unsigned short* __restrict__ Xhi, const unsigned short* __restrict__ Xlo,
    const unsigned short* __restrict__ wpack,
    const float* __restrict__ bias_self, const float* __restrict__ bias_neigh,
    float* __restrict__ out)
{
    __shared__ bf16x8 Wlds[2][4096];   // [hi/lo][8ct * 8ks * 64l], 128 KB
    int mt = blockIdx.x, ns = blockIdx.y, half = blockIdx.z;
    int b0 = mt * 256;
    int tid = threadIdx.x;

    const bf16x8* hsrc = (const bf16x8*)(wpack + (size_t)half * 131072 + (size_t)ns * 32768);
    const bf16x8* lsrc = (const bf16x8*)(wpack + (size_t)half * 131072 + 65536 + (size_t)ns * 32768);
#pragma unroll
    for (int it = 0; it < 8; ++it) {
        int i = it * 512 + tid;
        Wlds[0][i] = hsrc[i];
        Wlds[1][i] = lsrc[i];
    }
    __syncthreads();

    int w = tid >> 6, l = tid & 63;
    int mg = w >> 1;        // 0..3 : 64-row group
    int ng = w & 1;         // 0..1 : 4-ct group
    int colq = l & 15;
    int kq = l >> 4;

    const float* bias = half ? bias_neigh : bias_self;

    f32x4 acc[4][4];
#pragma unroll
    for (int c = 0; c < 4; ++c) {
        float bv = bias[(ns * 8 + ng * 4 + c) * 16 + colq];
#pragma unroll
        for (int m = 0; m < 4; ++m) acc[m][c] = {bv, bv, bv, bv};
    }

#pragma unroll
    for (int ks = 0; ks < 8; ++ks) {
        bf16x8 Ah[4], Al[4];
#pragma unroll
        for (int m = 0; m < 4; ++m) {
            size_t ao = (size_t)(b0 + mg * 64 + m * 16 + colq) * 512
                        + half * 256 + ks * 32 + kq * 8;
            Ah[m] = *(const bf16x8*)(Xhi + ao);
            Al[m] = *(const bf16x8*)(Xlo + ao);
        }
        bf16x8 Bh[4], Bl[4];
#pragma unroll
        for (int c = 0; c < 4; ++c) {
            int bi = (ng * 4 + c) * 512 + ks * 64 + l;
            Bh[c] = Wlds[0][bi];
            Bl[c] = Wlds[1][bi];
        }
#pragma unroll
        for (int c = 0; c < 4; ++c) {
#pragma unroll
            for (int m = 0; m < 4; ++m) {
                acc[m][c] = __builtin_amdgcn_mfma_f32_16x16x32_bf16(Ah[m], Bh[c], acc[m][c], 0, 0, 0);
                acc[m][c] = __builtin_amdgcn_mfma_f32_16x16x32_bf16(Al[m], Bh[c], acc[m][c], 0, 0, 0);
                acc[m][c] = __builtin_amdgcn_mfma_f32_16x16x32_bf16(Ah[m], Bl[c], acc[m][c], 0, 0, 0);
            }
        }
    }

    // epilogue: relu + store
#pragma unroll
    for (int m = 0; m < 4; ++m) {
#pragma unroll
        for (int c = 0; c < 4; ++c) {
            int row = b0 + mg * 64 + m * 16 + kq * 4;
            int col = half * 256 + (ns * 8 + ng * 4 + c) * 16 + colq;
            float* o = out + (size_t)row * 512 + col;
#pragma unroll
            for (int j = 0; j < 4; ++j) {
                o[(size_t)j * 512] = fmaxf(acc[m][c][j], 0.0f);
            }
        }
    }
}

// Fallback (ws too small): v1 in-place dual GEMM, X tile in LDS, B from global.
__global__ __launch_bounds__(256) void dual_gemm_inplace(
    const float* X, const unsigned short* __restrict__ wpack,
    const float* __restrict__ bias_self, const float* __restrict__ bias_neigh,
    float* out)
{
    __shared__ short Xh[64 * 256];
    __shared__ short Xl[64 * 256];
    int half = blockIdx.y;
    int b0 = blockIdx.x * 64;
    int tid = threadIdx.x;

    const unsigned short* Whi = wpack + (size_t)half * 131072;
    const unsigned short* Wlo = Whi + 65536;
    const float* bias = half ? bias_neigh : bias_self;

#pragma unroll
    for (int it = 0; it < 8; ++it) {
        int c = it * 256 + tid;
        int row = c >> 5;
        int k8 = c & 31;
        const float* src = X + (size_t)(b0 + row) * 512 + half * 256 + k8 * 8;
        f32x4 v0 = *(const f32x4*)src;
        f32x4 v1 = *(const f32x4*)(src + 4);
        bf16x8 hv, lv;
#pragma unroll
        for (int e = 0; e < 8; ++e) {
            float x = (e < 4) ? v0[e] : v1[e - 4];
            unsigned short h16 = bf16_rne(x);
            hv[e] = (short)h16;
            lv[e] = (short)bf16_rne(x - bf16_f(h16));
        }
        int boff = (row * 512 + k8 * 16) ^ ((row & 7) << 4);
        *(bf16x8*)((char*)Xh + boff) = hv;
        *(bf16x8*)((char*)Xl + boff) = lv;
    }
    __syncthreads();

    int w = tid >> 6, l = tid & 63;
    int mh = w & 1;
    int nh = w >> 1;
    int colq = l & 15;
    int kq = l >> 4;

    f32x4 acc[2][8];
#pragma unroll
    for (int c = 0; c < 8; ++c) {
        int ct = nh * 8 + c;
        float bv = bias[ct * 16 + colq];
#pragma unroll
        for (int m = 0; m < 2; ++m) acc[m][c] = {bv, bv, bv, bv};
    }

#pragma unroll
    for (int ks = 0; ks < 8; ++ks) {
        bf16x8 Ah[2], Al[2];
#pragma unroll
        for (int m = 0; m < 2; ++m) {
            int row = mh * 32 + m * 16 + colq;
            int boff = (row * 512 + ks * 64 + (kq << 4)) ^ ((row & 7) << 4);
            Ah[m] = *(const bf16x8*)((const char*)Xh + boff);
            Al[m] = *(const bf16x8*)((const char*)Xl + boff);
        }
#pragma unroll
        for (int c = 0; c < 8; ++c) {
            int ct = nh * 8 + c;
            size_t fo = ((size_t)(ct * 8 + ks) * 64 + l) * 8;
            bf16x8 Bh = *(const bf16x8*)(Whi + fo);
            bf16x8 Bl = *(const bf16x8*)(Wlo + fo);
#pragma unroll
            for (int m = 0; m < 2; ++m) {
                acc[m][c] = __builtin_amdgcn_mfma_f32_16x16x32_bf16(Ah[m], Bh, acc[m][c], 0, 0, 0);
                acc[m][c] = __builtin_amdgcn_mfma_f32_16x16x32_bf16(Al[m], Bh, acc[m][c], 0, 0, 0);
                acc[m][c] = __builtin_amdgcn_mfma_f32_16x16x32_bf16(Ah[m], Bl, acc[m][c], 0, 0, 0);
            }
        }
    }

#pragma unroll
    for (int m = 0; m < 2; ++m) {
        int rb = mh * 32 + m * 16 + (kq << 2);
#pragma unroll
        for (int c = 0; c < 8; ++c) {
            int col = (nh * 8 + c) * 16 + colq;
            float* o = out + (size_t)(b0 + rb) * 512 + half * 256 + col;
#pragma unroll
            for (int j = 0; j < 4; ++j) {
                o[(size_t)j * 512] = fmaxf(acc[m][c][j], 0.0f);
            }
        }
    }
}

extern "C" void kernel_launch(void* const* d_in, const int* in_sizes, int n_in,
                              void* d_out, int out_size, void* d_ws, size_t ws_size,
                              hipStream_t stream) {
    const int* x0 = (const int*)d_in[0];
    const int* x1 = (const int*)d_in[1];
    const float* emb = (const float*)d_in[2];
    const float* Wself = (const float*)d_in[3];
    const float* bself = (const float*)d_in[4];
    const float* Wneigh = (const float*)d_in[5];
    const float* bneigh = (const float*)d_in[6];
    float* out = (float*)d_out;
    unsigned short* wpack = (unsigned short*)d_ws;            // 512 KB
    const size_t wpack_bytes = 512 * 1024;
    const size_t xplane_bytes = (size_t)16384 * 512 * 2;      // 16.78 MB per plane

    pack_weights<<<dim3(32, 2), 256, 0, stream>>>(Wself, Wneigh, wpack);

    if (ws_size >= wpack_bytes + 2 * xplane_bytes) {
        unsigned short* Xhi = (unsigned short*)((char*)d_ws + wpack_bytes);
        unsigned short* Xlo = Xhi + (size_t)16384 * 512;
        gather_pool_split<<<16384, 256, 0, stream>>>(x0, x1, emb, Xhi, Xlo);
        dual_gemm_v3<<<dim3(64, 2, 2), 512, 0, stream>>>(Xhi, Xlo, wpack, bself, bneigh, out);
    } else {
        gather_pool<<<16384, 256, 0, stream>>>(x0, x1, emb, out);
        dual_gemm_inplace<<<dim3(256, 2), 256, 0, stream>>>(out, wpack, bself, bneigh, out);
    }
}